// Round 8
// baseline (66.828 us; speedup 1.0000x reference)
//
#include <hip/hip_runtime.h>

// DCN cross net, fully fused single kernel (round 7).
// Recurrence unroll (rounds 1-6) with per-wave inline constants:
//   q1=b0, q2=b0+b1, q3=b0+b1+b2, Bsum=q3+b3
//   C1=dot(q1,w1), C2=dot(q2,w2), C3=dot(q3,w3)
//   d_l = x0.w_l ;  s0=d0; s1=d1(1+s0)+C1; s2=d2(1+s0+s1)+C2; s3=d3(...)+C3
//   out = x0*(1+s0+s1+s2+s3) + Bsum
// Preamble loads (L2-hot, 28 float4) issue BEFORE the x loads so consuming
// them waits only vmcnt(8-ish) while HBM x-loads remain outstanding; the
// 3-value butterfly (DS pipe) overlaps x latency. No pre-kernel, no ws,
// no LDS, no barriers. 2 consecutive rows per wave, exact grid.

#define DCN_D 1024
#define DCN_F4 (DCN_D / 4)   // 256 float4 per row

__device__ __forceinline__ float dot4acc(const float4 a, const float4 b, float acc) {
    return fmaf(a.x, b.x, fmaf(a.y, b.y, fmaf(a.z, b.z, fmaf(a.w, b.w, acc))));
}

__global__ __launch_bounds__(256) void dcn_fused_kernel(
    const float* __restrict__ x,
    const float* __restrict__ w,   // [4, D]
    const float* __restrict__ b,   // [4, D]
    float* __restrict__ out,
    int B)
{
    const int wid  = (int)((blockIdx.x * 256u + threadIdx.x) >> 6);
    const int lane = (int)(threadIdx.x & 63);
    const int row0 = wid * 2;
    if (row0 >= B) return;

    const float4* __restrict__ w4 = reinterpret_cast<const float4*>(w);
    const float4* __restrict__ b4 = reinterpret_cast<const float4*>(b);

    // ---- preamble: per-wave constants (L2-hot loads, issued first) ----
    float4 bv[4];                 // Bsum at this wave's 4 j-positions
    float cp0 = 0.f, cp1 = 0.f, cp2 = 0.f;   // partials for C1,C2,C3
    #pragma unroll
    for (int j = 0; j < 4; ++j) {
        const int idx = lane + 64 * j;
        const float4 b0 = b4[idx];
        const float4 b1 = b4[DCN_F4 + idx];
        const float4 b2 = b4[2 * DCN_F4 + idx];
        const float4 b3 = b4[3 * DCN_F4 + idx];
        const float4 w1 = w4[DCN_F4 + idx];
        const float4 w2 = w4[2 * DCN_F4 + idx];
        const float4 w3 = w4[3 * DCN_F4 + idx];
        float4 q2, q3, q4;
        q2.x = b0.x + b1.x; q2.y = b0.y + b1.y; q2.z = b0.z + b1.z; q2.w = b0.w + b1.w;
        q3.x = q2.x + b2.x; q3.y = q2.y + b2.y; q3.z = q2.z + b2.z; q3.w = q2.w + b2.w;
        q4.x = q3.x + b3.x; q4.y = q3.y + b3.y; q4.z = q3.z + b3.z; q4.w = q3.w + b3.w;
        bv[j] = q4;
        cp0 = dot4acc(b0, w1, cp0);
        cp1 = dot4acc(q2, w2, cp1);
        cp2 = dot4acc(q3, w3, cp2);
    }

    // ---- x loads: 2 rows, 8 float4, HBM ----
    const float4* __restrict__ xr0 =
        reinterpret_cast<const float4*>(x + (size_t)row0 * DCN_D);
    const float4* __restrict__ xr1 =
        reinterpret_cast<const float4*>(x + (size_t)(row0 + 1) * DCN_D);
    float4 xa[4], xb[4];
    #pragma unroll
    for (int j = 0; j < 4; ++j) xa[j] = xr0[lane + 64 * j];
    #pragma unroll
    for (int j = 0; j < 4; ++j) xb[j] = xr1[lane + 64 * j];

    // ---- butterfly the 3 constant partials (DS pipe; overlaps x latency) ----
    #pragma unroll
    for (int off = 1; off < 64; off <<= 1) {
        cp0 += __shfl_xor(cp0, off, 64);
        cp1 += __shfl_xor(cp1, off, 64);
        cp2 += __shfl_xor(cp2, off, 64);
    }

    // ---- row dots (w reloaded from L1) ----
    float p0[4] = {0, 0, 0, 0}, p1[4] = {0, 0, 0, 0};
    #pragma unroll
    for (int j = 0; j < 4; ++j) {
        const int idx = lane + 64 * j;
        #pragma unroll
        for (int l = 0; l < 4; ++l) {
            const float4 wv = w4[l * DCN_F4 + idx];
            p0[l] = dot4acc(xa[j], wv, p0[l]);
            p1[l] = dot4acc(xb[j], wv, p1[l]);
        }
    }
    #pragma unroll
    for (int off = 1; off < 64; off <<= 1) {
        #pragma unroll
        for (int l = 0; l < 4; ++l) {
            p0[l] += __shfl_xor(p0[l], off, 64);
            p1[l] += __shfl_xor(p1[l], off, 64);
        }
    }

    // ---- scalar recurrence per row ----
    const float t1a = 1.f + p0[0];
    const float s1a = fmaf(p0[1], t1a, cp0);
    const float t2a = t1a + s1a;
    const float s2a = fmaf(p0[2], t2a, cp1);
    const float t3a = t2a + s2a;
    const float s3a = fmaf(p0[3], t3a, cp2);
    const float S0  = t3a + s3a;
    const float t1b = 1.f + p1[0];
    const float s1b = fmaf(p1[1], t1b, cp0);
    const float t2b = t1b + s1b;
    const float s2b = fmaf(p1[2], t2b, cp1);
    const float t3b = t2b + s2b;
    const float s3b = fmaf(p1[3], t3b, cp2);
    const float S1  = t3b + s3b;

    // ---- store ----
    float4* __restrict__ o0 = reinterpret_cast<float4*>(out + (size_t)row0 * DCN_D);
    float4* __restrict__ o1 = reinterpret_cast<float4*>(out + (size_t)(row0 + 1) * DCN_D);
    #pragma unroll
    for (int j = 0; j < 4; ++j) {
        const int idx = lane + 64 * j;
        float4 a;
        a.x = fmaf(xa[j].x, S0, bv[j].x);
        a.y = fmaf(xa[j].y, S0, bv[j].y);
        a.z = fmaf(xa[j].z, S0, bv[j].z);
        a.w = fmaf(xa[j].w, S0, bv[j].w);
        o0[idx] = a;
        float4 c;
        c.x = fmaf(xb[j].x, S1, bv[j].x);
        c.y = fmaf(xb[j].y, S1, bv[j].y);
        c.z = fmaf(xb[j].z, S1, bv[j].z);
        c.w = fmaf(xb[j].w, S1, bv[j].w);
        o1[idx] = c;
    }
}

extern "C" void kernel_launch(void* const* d_in, const int* in_sizes, int n_in,
                              void* d_out, int out_size, void* d_ws, size_t ws_size,
                              hipStream_t stream) {
    const float* x = (const float*)d_in[0];
    const float* w = (const float*)d_in[1];
    const float* b = (const float*)d_in[2];
    float* out = (float*)d_out;
    const int B = in_sizes[0] / DCN_D;

    // single fused kernel: 2 rows per wave, 4 waves per block -> 8 rows/block
    const int rows_per_block = 8;
    dcn_fused_kernel<<<(B + rows_per_block - 1) / rows_per_block, 256, 0, stream>>>(
        x, w, b, out, B);
}

// Round 9
// 50.429 us; speedup vs baseline: 1.3252x; 1.3252x over previous
//
#include <hip/hip_runtime.h>

// DCN cross net, algebraically unrolled (rounds 1-4). Round 8:
//  - round-4 structure (pre-kernel + 2 rows/wave) BUT w + Bsum staged in LDS
//    once per block (20 KB): steady-state VMEM per wave is exactly 8 HBM
//    loads + 8 stores (copy-shaped); the 20 broadcast w/bias reads move to
//    the idle DS pipe, freeing L1/TA for the x/out stream.
//  - x loads issued before staging so they ride out the staging barrier.
//  - 2 rows per wave, 4 waves/block -> 8 rows/block, exact grid.

#define DCN_D 1024
#define DCN_F4 (DCN_D / 4)   // 256 float4 per row

// ws layout: ws[0..1023] = Bsum; ws[1024..1029] = {c01,c02,c12,c03,c13,c23}

__global__ __launch_bounds__(256) void dcn_pre_kernel(
    const float* __restrict__ w,   // [4, D]
    const float* __restrict__ b,   // [4, D]
    float* __restrict__ ws)
{
    const int t = threadIdx.x;
    for (int d = t; d < DCN_D; d += 256)
        ws[d] = b[d] + b[DCN_D + d] + b[2 * DCN_D + d] + b[3 * DCN_D + d];
    float p[6] = {0, 0, 0, 0, 0, 0};
    for (int d = t; d < DCN_D; d += 256) {
        const float b0 = b[d], b1 = b[DCN_D + d], b2 = b[2 * DCN_D + d];
        const float w1 = w[DCN_D + d], w2 = w[2 * DCN_D + d], w3 = w[3 * DCN_D + d];
        p[0] = fmaf(b0, w1, p[0]);
        p[1] = fmaf(b0, w2, p[1]);
        p[2] = fmaf(b1, w2, p[2]);
        p[3] = fmaf(b0, w3, p[3]);
        p[4] = fmaf(b1, w3, p[4]);
        p[5] = fmaf(b2, w3, p[5]);
    }
    __shared__ float red[6][4];
    const int wave = t >> 6, lane = t & 63;
    #pragma unroll
    for (int k = 0; k < 6; ++k) {
        float v = p[k];
        #pragma unroll
        for (int off = 32; off > 0; off >>= 1) v += __shfl_down(v, off, 64);
        if (lane == 0) red[k][wave] = v;
    }
    __syncthreads();
    if (t < 6) ws[DCN_D + t] = red[t][0] + red[t][1] + red[t][2] + red[t][3];
}

__device__ __forceinline__ float dot4acc(const float4 a, const float4 b, float acc) {
    return fmaf(a.x, b.x, fmaf(a.y, b.y, fmaf(a.z, b.z, fmaf(a.w, b.w, acc))));
}

__global__ __launch_bounds__(256) void dcn_main_kernel(
    const float* __restrict__ x,
    const float* __restrict__ w,
    const float* __restrict__ ws,
    float* __restrict__ out,
    int B)
{
    __shared__ float4 w_lds[4 * DCN_F4];   // 16 KB
    __shared__ float4 b_lds[DCN_F4];       //  4 KB

    const int t    = (int)threadIdx.x;
    const int lane = t & 63;
    const int wib  = t >> 6;                       // wave-in-block
    const int row0 = ((int)blockIdx.x * 4 + wib) * 2;
    const bool live = row0 < B;
    const bool has2 = (row0 + 1) < B;

    // ---- x loads first (HBM; stay in flight across the staging barrier) ----
    float4 xa[4], xb[4];
    if (live) {
        const float4* __restrict__ xr0 =
            reinterpret_cast<const float4*>(x + (size_t)row0 * DCN_D);
        const float4* __restrict__ xr1 =
            reinterpret_cast<const float4*>(x + (size_t)(has2 ? row0 + 1 : row0) * DCN_D);
        #pragma unroll
        for (int j = 0; j < 4; ++j) xa[j] = xr0[lane + 64 * j];
        #pragma unroll
        for (int j = 0; j < 4; ++j) xb[j] = xr1[lane + 64 * j];
    }

    // ---- stage w + Bsum into LDS (once per block, L2-broadcast) ----
    const float4* __restrict__ w4  = reinterpret_cast<const float4*>(w);
    const float4* __restrict__ bs4 = reinterpret_cast<const float4*>(ws);
    #pragma unroll
    for (int i = 0; i < 4; ++i) w_lds[t + 256 * i] = w4[t + 256 * i];
    b_lds[t] = bs4[t];
    // uniform scalars (scalar loads, constant-cached)
    const float c01   = ws[DCN_D + 0];
    const float c2sum = ws[DCN_D + 1] + ws[DCN_D + 2];
    const float c3sum = ws[DCN_D + 3] + ws[DCN_D + 4] + ws[DCN_D + 5];
    __syncthreads();

    if (!live) return;

    // ---- row dots: w from LDS (DS pipe), x in registers ----
    float p0[4] = {0, 0, 0, 0}, p1[4] = {0, 0, 0, 0};
    #pragma unroll
    for (int j = 0; j < 4; ++j) {
        const int idx = lane + 64 * j;
        #pragma unroll
        for (int l = 0; l < 4; ++l) {
            const float4 wv = w_lds[l * DCN_F4 + idx];
            p0[l] = dot4acc(xa[j], wv, p0[l]);
            p1[l] = dot4acc(xb[j], wv, p1[l]);
        }
    }

    // ---- butterfly reductions (8 independent, pipelined) ----
    #pragma unroll
    for (int off = 1; off < 64; off <<= 1) {
        #pragma unroll
        for (int l = 0; l < 4; ++l) {
            p0[l] += __shfl_xor(p0[l], off, 64);
            p1[l] += __shfl_xor(p1[l], off, 64);
        }
    }

    // ---- scalar recurrence ----
    const float t1a = 1.f + p0[0];
    const float s1a = fmaf(p0[1], t1a, c01);
    const float t2a = t1a + s1a;
    const float s2a = fmaf(p0[2], t2a, c2sum);
    const float t3a = t2a + s2a;
    const float s3a = fmaf(p0[3], t3a, c3sum);
    const float S0  = t3a + s3a;
    const float t1b = 1.f + p1[0];
    const float s1b = fmaf(p1[1], t1b, c01);
    const float t2b = t1b + s1b;
    const float s2b = fmaf(p1[2], t2b, c2sum);
    const float t3b = t2b + s2b;
    const float s3b = fmaf(p1[3], t3b, c3sum);
    const float S1  = t3b + s3b;

    // ---- store (bias from LDS) ----
    float4* __restrict__ o0 = reinterpret_cast<float4*>(out + (size_t)row0 * DCN_D);
    float4* __restrict__ o1 = reinterpret_cast<float4*>(out + (size_t)(row0 + 1) * DCN_D);
    #pragma unroll
    for (int j = 0; j < 4; ++j) {
        const int idx = lane + 64 * j;
        const float4 bb = b_lds[idx];
        float4 a;
        a.x = fmaf(xa[j].x, S0, bb.x);
        a.y = fmaf(xa[j].y, S0, bb.y);
        a.z = fmaf(xa[j].z, S0, bb.z);
        a.w = fmaf(xa[j].w, S0, bb.w);
        o0[idx] = a;
        if (has2) {
            float4 c;
            c.x = fmaf(xb[j].x, S1, bb.x);
            c.y = fmaf(xb[j].y, S1, bb.y);
            c.z = fmaf(xb[j].z, S1, bb.z);
            c.w = fmaf(xb[j].w, S1, bb.w);
            o1[idx] = c;
        }
    }
}

extern "C" void kernel_launch(void* const* d_in, const int* in_sizes, int n_in,
                              void* d_out, int out_size, void* d_ws, size_t ws_size,
                              hipStream_t stream) {
    const float* x = (const float*)d_in[0];
    const float* w = (const float*)d_in[1];
    const float* b = (const float*)d_in[2];
    float* out = (float*)d_out;
    float* ws = (float*)d_ws;
    const int B = in_sizes[0] / DCN_D;

    dcn_pre_kernel<<<1, 256, 0, stream>>>(w, b, ws);
    // 2 rows/wave, 4 waves/block -> 8 rows per block
    const int rows_per_block = 8;
    dcn_main_kernel<<<(B + rows_per_block - 1) / rows_per_block, 256, 0, stream>>>(
        x, w, ws, out, B);
}